// Round 5
// baseline (480.591 us; speedup 1.0000x reference)
//
#include <hip/hip_runtime.h>
#include <cstdint>
#include <cstddef>

typedef __bf16 bf16x8 __attribute__((ext_vector_type(8)));
typedef __bf16 bf16x4 __attribute__((ext_vector_type(4)));
typedef float f32x4 __attribute__((ext_vector_type(4)));

__device__ __forceinline__ uint16_t f2bf(float f) {
    union { float f; uint32_t u; } v; v.f = f;
    uint32_t r = (v.u + 0x7fffu + ((v.u >> 16) & 1u)) >> 16;
    return (uint16_t)r;
}
__device__ __forceinline__ float bf2f(uint16_t h) {
    union { uint32_t u; float f; } v; v.u = ((uint32_t)h) << 16;
    return v.f;
}

// async 16B/lane global->LDS (wave-uniform LDS base; HW scatters lane i at +16i)
__device__ __forceinline__ void gload_lds16(const void* g, void* l) {
    __builtin_amdgcn_global_load_lds(
        (__attribute__((address_space(1))) void*)g,
        (__attribute__((address_space(3))) void*)l, 16, 0, 0);
}

// ---------------------------------------------------------------------------
// hidden fp32 -> bf16
// ---------------------------------------------------------------------------
__global__ __launch_bounds__(256) void k_tobf16(const float* __restrict__ X,
                                                uint16_t* __restrict__ Y) {
    int i = (blockIdx.x * 256 + threadIdx.x) * 4;
    f32x4 v = *reinterpret_cast<const f32x4*>(X + i);
    uint2 o;
    o.x = (uint32_t)f2bf(v[0]) | ((uint32_t)f2bf(v[1]) << 16);
    o.y = (uint32_t)f2bf(v[2]) | ((uint32_t)f2bf(v[3]) << 16);
    *reinterpret_cast<uint2*>(Y + i) = o;
}

// ---------------------------------------------------------------------------
// Weight transpose + convert: W (R x C, fp32) -> Wt (C x R, bf16)
// ---------------------------------------------------------------------------
__global__ __launch_bounds__(256) void k_transpose_w(const float* __restrict__ W,
                                                     uint16_t* __restrict__ Wt,
                                                     int R, int C) {
    __shared__ uint16_t tile[32][33];
    int c0 = blockIdx.x * 32;
    int r0 = blockIdx.y * 32;
    int t = threadIdx.x;
    int tc = t & 31, tr = t >> 5;
#pragma unroll
    for (int i = 0; i < 4; ++i) {
        int r = tr * 4 + i;
        tile[r][tc] = f2bf(W[(size_t)(r0 + r) * C + c0 + tc]);
    }
    __syncthreads();
#pragma unroll
    for (int i = 0; i < 4; ++i) {
        int c = tr * 4 + i;
        Wt[(size_t)(c0 + c) * R + r0 + tc] = tile[tc][c];
    }
}

// ---------------------------------------------------------------------------
// V transpose: V (2048 x 512 bf16) -> Vt (4 x 128 x 2048 bf16)
// ---------------------------------------------------------------------------
__global__ __launch_bounds__(256) void k_transpose_v(const uint16_t* __restrict__ V,
                                                     uint16_t* __restrict__ Vt) {
    __shared__ uint16_t tile[32][33];
    int c0 = blockIdx.x * 32;
    int s0 = blockIdx.y * 32;
    int t = threadIdx.x;
    int tc = t & 31, tr = t >> 5;
#pragma unroll
    for (int i = 0; i < 4; ++i) {
        int s = tr * 4 + i;
        tile[s][tc] = V[(size_t)(s0 + s) * 512 + c0 + tc];
    }
    __syncthreads();
#pragma unroll
    for (int i = 0; i < 4; ++i) {
        int c = c0 + tr * 4 + i;
        Vt[(size_t)c * 2048 + s0 + tc] = tile[tc][tr * 4 + i];
    }
}

// ---------------------------------------------------------------------------
// RoPE in place. Q scaled by (1/sqrt(128))*log2(e) for exp2-domain softmax.
// ---------------------------------------------------------------------------
__global__ __launch_bounds__(256) void k_rope(uint16_t* __restrict__ Q,
                                              uint16_t* __restrict__ K,
                                              const int* __restrict__ pos_ids) {
    int idx = blockIdx.x * 256 + threadIdx.x;
    int d = idx & 63;
    int s = idx >> 6;
    float pos = (float)pos_ids[s];
    float ang = pos * exp2f((float)d * (-19.931568569324174f / 64.0f));
    float cs = cosf(ang), sn = sinf(ang);
    const float qscale = 0.08838834764831845f * 1.4426950408889634f;
    uint16_t* q = Q + (size_t)s * 3584 + d;
#pragma unroll
    for (int h = 0; h < 28; ++h) {
        float x1 = bf2f(q[h * 128]);
        float x2 = bf2f(q[h * 128 + 64]);
        q[h * 128]      = f2bf((x1 * cs - x2 * sn) * qscale);
        q[h * 128 + 64] = f2bf((x2 * cs + x1 * sn) * qscale);
    }
    uint16_t* k = K + (size_t)s * 512 + d;
#pragma unroll
    for (int h = 0; h < 4; ++h) {
        float x1 = bf2f(k[h * 128]);
        float x2 = bf2f(k[h * 128 + 64]);
        k[h * 128]      = f2bf(x1 * cs - x2 * sn);
        k[h * 128 + 64] = f2bf(x2 * cs + x1 * sn);
    }
}

// ---------------------------------------------------------------------------
// m97-style GEMM: 128x128 tile, BK=32, global_load_lds width-16 staging.
// T1 XCD swizzle kept (neutral-to-small-positive, zero risk).
// ---------------------------------------------------------------------------
#define BK 32

__global__ __launch_bounds__(256) void k_gemm_qkv(
    const uint16_t* __restrict__ A,
    const uint16_t* __restrict__ WqT,
    const uint16_t* __restrict__ WkT,
    const uint16_t* __restrict__ WvT,
    uint16_t* __restrict__ Q,
    uint16_t* __restrict__ K,
    uint16_t* __restrict__ V)
{
    __shared__ uint16_t Als[128 * BK];
    __shared__ uint16_t Bls[128 * BK];

    int bid = blockIdx.x + blockIdx.y * 36;          // 0..575
    int rid = (bid & 7) * 72 + (bid >> 3);           // XCD-chunked remap
    int nt = rid % 36;
    int m0 = (rid / 36) * 128;

    const uint16_t* Bt; uint16_t* dst; int dstStride; int colBase;
    if (nt < 28)      { Bt = WqT + (size_t)nt * 128 * 3584;        dst = Q; dstStride = 3584; colBase = nt * 128; }
    else if (nt < 32) { Bt = WkT + (size_t)(nt - 28) * 128 * 3584; dst = K; dstStride = 512;  colBase = (nt - 28) * 128; }
    else              { Bt = WvT + (size_t)(nt - 32) * 128 * 3584; dst = V; dstStride = 512;  colBase = (nt - 32) * 128; }

    int tid = threadIdx.x;
    int w = tid >> 6, lane = tid & 63, quad = lane >> 4, l15 = lane & 15;
    int wm = (w >> 1) * 64, wn = (w & 1) * 64;

    int lrow = lane >> 2;
    int lcol = (lane & 3) * 8;

    const uint16_t* aS = A  + (size_t)(m0 + w * 32 + lrow) * 3584 + lcol;
    const uint16_t* bS = Bt + (size_t)(w * 32 + lrow) * 3584 + lcol;
    uint16_t* aD0 = &Als[(w * 32) * BK];
    uint16_t* aD1 = &Als[(w * 32 + 16) * BK];
    uint16_t* bD0 = &Bls[(w * 32) * BK];
    uint16_t* bD1 = &Bls[(w * 32 + 16) * BK];

    f32x4 acc[4][4] = {};

    for (int k0 = 0; k0 < 3584; k0 += BK) {
        __syncthreads();
        gload_lds16(aS + k0, aD0);
        gload_lds16(aS + k0 + (size_t)16 * 3584, aD1);
        gload_lds16(bS + k0, bD0);
        gload_lds16(bS + k0 + (size_t)16 * 3584, bD1);
        __syncthreads();

        bf16x8 af[4], bfr[4];
#pragma unroll
        for (int i = 0; i < 4; ++i)
            af[i] = *reinterpret_cast<const bf16x8*>(&Als[(wm + i * 16 + l15) * BK + quad * 8]);
#pragma unroll
        for (int j = 0; j < 4; ++j)
            bfr[j] = *reinterpret_cast<const bf16x8*>(&Bls[(wn + j * 16 + l15) * BK + quad * 8]);
#pragma unroll
        for (int i = 0; i < 4; ++i)
#pragma unroll
            for (int j = 0; j < 4; ++j)
                acc[i][j] = __builtin_amdgcn_mfma_f32_16x16x32_bf16(af[i], bfr[j], acc[i][j], 0, 0, 0);
    }

#pragma unroll
    for (int i = 0; i < 4; ++i)
#pragma unroll
        for (int r = 0; r < 4; ++r) {
            int grow = m0 + wm + i * 16 + quad * 4 + r;
#pragma unroll
            for (int j = 0; j < 4; ++j) {
                int gcol = colBase + wn + j * 16 + l15;
                dst[(size_t)grow * dstStride + gcol] = f2bf(acc[i][j][r]);
            }
        }
}

__global__ __launch_bounds__(256) void k_gemm_o(
    const uint16_t* __restrict__ A,
    const uint16_t* __restrict__ WoT,
    float* __restrict__ out)
{
    __shared__ uint16_t Als[128 * BK];
    __shared__ uint16_t Bls[128 * BK];

    int bid = blockIdx.x + blockIdx.y * 28;          // 0..447
    int rid = (bid & 7) * 56 + (bid >> 3);           // XCD-chunked remap
    int nt = rid % 28;
    int m0 = (rid / 28) * 128;
    const uint16_t* Bt = WoT + (size_t)nt * 128 * 3584;

    int tid = threadIdx.x;
    int w = tid >> 6, lane = tid & 63, quad = lane >> 4, l15 = lane & 15;
    int wm = (w >> 1) * 64, wn = (w & 1) * 64;

    int lrow = lane >> 2;
    int lcol = (lane & 3) * 8;

    const uint16_t* aS = A  + (size_t)(m0 + w * 32 + lrow) * 3584 + lcol;
    const uint16_t* bS = Bt + (size_t)(w * 32 + lrow) * 3584 + lcol;
    uint16_t* aD0 = &Als[(w * 32) * BK];
    uint16_t* aD1 = &Als[(w * 32 + 16) * BK];
    uint16_t* bD0 = &Bls[(w * 32) * BK];
    uint16_t* bD1 = &Bls[(w * 32 + 16) * BK];

    f32x4 acc[4][4] = {};

    for (int k0 = 0; k0 < 3584; k0 += BK) {
        __syncthreads();
        gload_lds16(aS + k0, aD0);
        gload_lds16(aS + k0 + (size_t)16 * 3584, aD1);
        gload_lds16(bS + k0, bD0);
        gload_lds16(bS + k0 + (size_t)16 * 3584, bD1);
        __syncthreads();

        bf16x8 af[4], bfr[4];
#pragma unroll
        for (int i = 0; i < 4; ++i)
            af[i] = *reinterpret_cast<const bf16x8*>(&Als[(wm + i * 16 + l15) * BK + quad * 8]);
#pragma unroll
        for (int j = 0; j < 4; ++j)
            bfr[j] = *reinterpret_cast<const bf16x8*>(&Bls[(wn + j * 16 + l15) * BK + quad * 8]);
#pragma unroll
        for (int i = 0; i < 4; ++i)
#pragma unroll
            for (int j = 0; j < 4; ++j)
                acc[i][j] = __builtin_amdgcn_mfma_f32_16x16x32_bf16(af[i], bfr[j], acc[i][j], 0, 0, 0);
    }

#pragma unroll
    for (int i = 0; i < 4; ++i)
#pragma unroll
        for (int r = 0; r < 4; ++r) {
            int grow = m0 + wm + i * 16 + quad * 4 + r;
#pragma unroll
            for (int j = 0; j < 4; ++j) {
                int gcol = nt * 128 + wn + j * 16 + l15;
                out[(size_t)grow * 3584 + gcol] = acc[i][j][r];
            }
        }
}

// ---------------------------------------------------------------------------
// Flash attention, split-K within block, SWAPPED QK^T (m214 technique).
// sc = mfma(K, Q) -> D[key][q]: col=l15=q (one q-row per lane), row=quad*4+r
// +nt*16 = key. Row stats (m,l) are lane-resident scalars; reductions are a
// 7-op in-lane tree + shfl_xor(16) + shfl_xor(32) instead of 4-deep DPP
// chains; P-store is 2 packed 8B ds_writes per s (contiguous keys per lane)
// instead of 16 scalar 2B writes. PV and the cross-wave combine epilogue are
// unchanged (acc layout identical: row=q=quad*4+r, col=d=l15).
// T13 defer-rescale: rare acc-rescale fetches per-row alf via 4 shfls.
// ---------------------------------------------------------------------------
#define FPLD 40

__global__ __launch_bounds__(256, 2) void k_flash(
    const uint16_t* __restrict__ Q,    // 2048x3584 (roped, *1/sqrt(d)*log2e)
    const uint16_t* __restrict__ K,    // 2048x512  (roped)
    const uint16_t* __restrict__ Vt,   // 4x128x2048
    uint16_t* __restrict__ O)          // 2048x3584
{
    __shared__ uint16_t Pls[4][32 * FPLD];
    __shared__ uint16_t AccS[4][32 * 128];
    __shared__ float    Ml[4][32][2];

    int h  = blockIdx.x;               // 0..27
    int qb = 63 - (int)blockIdx.y;     // heavy first
    int kvh = h / 7;
    int tid = threadIdx.x;
    int w = tid >> 6, lane = tid & 63, quad = lane >> 4, l15 = lane & 15;
    int q0 = qb * 32;

    const uint16_t* Kh = K + kvh * 128;
    const uint16_t* Vh = Vt + (size_t)kvh * 128 * 2048;
    __bf16* Pw = reinterpret_cast<__bf16*>(&Pls[w][0]);

    // Q fragments: 32 rows (2 x 16). Same register layout serves as the
    // B-operand of the swapped mfma (lane l15 -> q-row).
    bf16x8 qf[2][4];
#pragma unroll
    for (int s = 0; s < 2; ++s) {
        const uint16_t* qp = Q + (size_t)(q0 + s * 16 + l15) * 3584 + h * 128 + quad * 8;
#pragma unroll
        for (int c = 0; c < 4; ++c)
            qf[s][c] = *reinterpret_cast<const bf16x8*>(qp + c * 32);
    }

    f32x4 acc[2][8] = {};
    float m_i[2], l_i[2];
    m_i[0] = m_i[1] = -1e30f;
    l_i[0] = l_i[1] = 0.f;

    int tmax = qb;                     // tiles 0..qb (32 keys each)
    bf16x8 kf[8];
    int t = w;
    if (t <= tmax) {                   // prefetch first owned K tile
        const uint16_t* kp = Kh + (size_t)(t * 32 + l15) * 512 + quad * 8;
#pragma unroll
        for (int nt = 0; nt < 2; ++nt)
#pragma unroll
            for (int c = 0; c < 4; ++c)
                kf[nt * 4 + c] = *reinterpret_cast<const bf16x8*>(kp + (size_t)nt * 16 * 512 + c * 32);
    }

    for (; t <= tmax; t += 4) {
        int kb = t * 32;
        // V frags issued now, consumed after softmax (latency hidden)
        bf16x8 vf[8];
        const uint16_t* vp = Vh + (size_t)l15 * 2048 + kb + quad * 8;
#pragma unroll
        for (int dt = 0; dt < 8; ++dt)
            vf[dt] = *reinterpret_cast<const bf16x8*>(vp + (size_t)dt * 16 * 2048);

        // QK^T swapped: sc[s][nt][r] = S[key=kb+nt*16+quad*4+r][q=q0+s*16+l15]
        f32x4 sc[2][2] = {};
#pragma unroll
        for (int nt = 0; nt < 2; ++nt)
#pragma unroll
            for (int c = 0; c < 4; ++c) {
                sc[0][nt] = __builtin_amdgcn_mfma_f32_16x16x32_bf16(kf[nt * 4 + c], qf[0][c], sc[0][nt], 0, 0, 0);
                sc[1][nt] = __builtin_amdgcn_mfma_f32_16x16x32_bf16(kf[nt * 4 + c], qf[1][c], sc[1][nt], 0, 0, 0);
            }

        // prefetch next owned K tile (hidden under softmax + PV)
        int tn = t + 4;
        if (tn <= tmax) {
            const uint16_t* kp = Kh + (size_t)(tn * 32 + l15) * 512 + quad * 8;
#pragma unroll
            for (int nt = 0; nt < 2; ++nt)
#pragma unroll
                for (int c = 0; c < 4; ++c)
                    kf[nt * 4 + c] = *reinterpret_cast<const bf16x8*>(kp + (size_t)nt * 16 * 512 + c * 32);
        }

        // causal mask (only possible on the last tile: kb+31 > q0)
        if (kb + 31 > q0) {
#pragma unroll
            for (int s = 0; s < 2; ++s) {
                int row = q0 + s * 16 + l15;
#pragma unroll
                for (int nt = 0; nt < 2; ++nt) {
                    int keyb = kb + nt * 16 + quad * 4;
#pragma unroll
                    for (int r = 0; r < 4; ++r)
                        if (keyb + r > row) sc[s][nt][r] = -1e30f;
                }
            }
        }

        // online softmax: lane owns one q-row per s. In-lane 8-value tree +
        // shfl_xor(16) + shfl_xor(32) -> all lanes hold full row stats.
#pragma unroll
        for (int s = 0; s < 2; ++s) {
            float mx = fmaxf(fmaxf(fmaxf(sc[s][0][0], sc[s][0][1]), fmaxf(sc[s][0][2], sc[s][0][3])),
                             fmaxf(fmaxf(sc[s][1][0], sc[s][1][1]), fmaxf(sc[s][1][2], sc[s][1][3])));
            mx = fmaxf(mx, __shfl_xor(mx, 16));
            mx = fmaxf(mx, __shfl_xor(mx, 32));
            // T13: keep old max unless growth > ~8 nats (11.5 in exp2 domain)
            bool nd = mx > m_i[s] + 11.5f;
            float mn = nd ? mx : m_i[s];
            float alf = __builtin_amdgcn_exp2f(m_i[s] - mn);   // ==1.0 when !nd
            m_i[s] = mn;

            float rs = 0.f;
#pragma unroll
            for (int nt = 0; nt < 2; ++nt)
#pragma unroll
                for (int r = 0; r < 4; ++r) {
                    float p = __builtin_amdgcn_exp2f(sc[s][nt][r] - mn);
                    sc[s][nt][r] = p;
                    rs += p;
                }
            rs += __shfl_xor(rs, 16);
            rs += __shfl_xor(rs, 32);
            l_i[s] = l_i[s] * alf + rs;

            if (__any(nd)) {           // rare: rescale acc rows (q=quad*4+r)
                f32x4 alfr;
#pragma unroll
                for (int r = 0; r < 4; ++r)
                    alfr[r] = __shfl(alf, quad * 4 + r);  // stats lane for that q
#pragma unroll
                for (int dt = 0; dt < 8; ++dt)
                    acc[s][dt] *= alfr;
            }

            // packed P-store: row q=s*16+l15, keys nt*16+quad*4..+3 (8B each)
#pragma unroll
            for (int nt = 0; nt < 2; ++nt) {
                bf16x4 pk;
#pragma unroll
                for (int r = 0; r < 4; ++r) pk[r] = (__bf16)sc[s][nt][r];
                *reinterpret_cast<bf16x4*>(&Pw[(s * 16 + l15) * FPLD + nt * 16 + quad * 4]) = pk;
            }
        }

        // PV: 32 q x 128 d over 32 keys (wave-private LDS, in-wave ordering)
        bf16x8 pf0 = *reinterpret_cast<const bf16x8*>(&Pw[l15 * FPLD + quad * 8]);
        bf16x8 pf1 = *reinterpret_cast<const bf16x8*>(&Pw[(16 + l15) * FPLD + quad * 8]);
#pragma unroll
        for (int dt = 0; dt < 8; ++dt) {
            acc[0][dt] = __builtin_amdgcn_mfma_f32_16x16x32_bf16(pf0, vf[dt], acc[0][dt], 0, 0, 0);
            acc[1][dt] = __builtin_amdgcn_mfma_f32_16x16x32_bf16(pf1, vf[dt], acc[1][dt], 0, 0, 0);
        }
    }

    // ---- write partials and combine across the 4 waves ----
    {
        __bf16* As = reinterpret_cast<__bf16*>(&AccS[w][0]);
#pragma unroll
        for (int s = 0; s < 2; ++s)
#pragma unroll
            for (int dt = 0; dt < 8; ++dt)
#pragma unroll
                for (int r = 0; r < 4; ++r)
                    As[(s * 16 + quad * 4 + r) * 128 + dt * 16 + l15] = (__bf16)acc[s][dt][r];
    }
    if (lane < 16) {                   // quad 0 lanes hold full stats for q=l15
        Ml[w][lane][0]      = m_i[0];
        Ml[w][lane][1]      = l_i[0];
        Ml[w][16 + lane][0] = m_i[1];
        Ml[w][16 + lane][1] = l_i[1];
    }
    __syncthreads();

    // combine: wave w handles rows w*8..w*8+7; lane -> (row, 16-col chunk)
    {
        int rowl = w * 8 + (lane >> 3);
        int c16 = (lane & 7) * 16;
        float m0 = Ml[0][rowl][0], m1 = Ml[1][rowl][0], m2 = Ml[2][rowl][0], m3 = Ml[3][rowl][0];
        float M = fmaxf(fmaxf(m0, m1), fmaxf(m2, m3));
        float s0 = __builtin_amdgcn_exp2f(m0 - M);
        float s1 = __builtin_amdgcn_exp2f(m1 - M);
        float s2 = __builtin_amdgcn_exp2f(m2 - M);
        float s3 = __builtin_amdgcn_exp2f(m3 - M);
        float lt = Ml[0][rowl][1] * s0 + Ml[1][rowl][1] * s1 +
                   Ml[2][rowl][1] * s2 + Ml[3][rowl][1] * s3;
        float inv = __builtin_amdgcn_rcpf(lt);
        float sw[4] = {s0, s1, s2, s3};

        float o[16];
#pragma unroll
        for (int j = 0; j < 16; ++j) o[j] = 0.f;
#pragma unroll
        for (int sl = 0; sl < 4; ++sl) {
            const uint16_t* src = &AccS[sl][rowl * 128 + c16];
            float ssc = sw[sl];
#pragma unroll
            for (int j = 0; j < 16; ++j)
                o[j] += bf2f(src[j]) * ssc;
        }
        uint16_t ob[16];
#pragma unroll
        for (int j = 0; j < 16; ++j) ob[j] = f2bf(o[j] * inv);
        uint16_t* op = O + (size_t)(q0 + rowl) * 3584 + h * 128 + c16;
        *reinterpret_cast<uint4*>(op)     = *reinterpret_cast<uint4*>(&ob[0]);
        *reinterpret_cast<uint4*>(op + 8) = *reinterpret_cast<uint4*>(&ob[8]);
    }
}

// ---------------------------------------------------------------------------
extern "C" void kernel_launch(void* const* d_in, const int* in_sizes, int n_in,
                              void* d_out, int out_size, void* d_ws, size_t ws_size,
                              hipStream_t stream) {
    const float* hidden = (const float*)d_in[0];
    const int*   pos    = (const int*)d_in[1];
    const float* Wq     = (const float*)d_in[2];
    const float* Wk     = (const float*)d_in[3];
    const float* Wv     = (const float*)d_in[4];
    const float* Wo     = (const float*)d_in[5];
    float* out = (float*)d_out;

    char* ws = (char*)d_ws;
    size_t o = 0;
    uint16_t* WqT = (uint16_t*)(ws + o); o += (size_t)3584 * 3584 * 2;
    uint16_t* WkT = (uint16_t*)(ws + o); o += (size_t)512  * 3584 * 2;
    uint16_t* WvT = (uint16_t*)(ws + o); o += (size_t)512  * 3584 * 2;
    uint16_t* WoT = (uint16_t*)(ws + o); o += (size_t)3584 * 3584 * 2;
    uint16_t* Xb  = (uint16_t*)(ws + o); o += (size_t)2048 * 3584 * 2;  // aliased as At
    uint16_t* Qb  = (uint16_t*)(ws + o); o += (size_t)2048 * 3584 * 2;
    uint16_t* Kb  = (uint16_t*)(ws + o); o += (size_t)2048 * 512  * 2;
    uint16_t* Vb  = (uint16_t*)(ws + o); o += (size_t)2048 * 512  * 2;
    uint16_t* Vt  = (uint16_t*)(ws + o); o += (size_t)2048 * 512  * 2;
    uint16_t* At  = Xb;

    k_tobf16<<<dim3(7168), 256, 0, stream>>>(hidden, Xb);
    k_transpose_w<<<dim3(112, 112), 256, 0, stream>>>(Wq, WqT, 3584, 3584);
    k_transpose_w<<<dim3(16, 112),  256, 0, stream>>>(Wk, WkT, 3584, 512);
    k_transpose_w<<<dim3(16, 112),  256, 0, stream>>>(Wv, WvT, 3584, 512);
    k_transpose_w<<<dim3(112, 112), 256, 0, stream>>>(Wo, WoT, 3584, 3584);

    k_gemm_qkv<<<dim3(36, 16), 256, 0, stream>>>(Xb, WqT, WkT, WvT, Qb, Kb, Vb);
    k_rope<<<dim3(512), 256, 0, stream>>>(Qb, Kb, pos);
    k_transpose_v<<<dim3(16, 64), 256, 0, stream>>>(Vb, Vt);
    k_flash<<<dim3(28, 64), 256, 0, stream>>>(Qb, Kb, Vt, At);
    k_gemm_o<<<dim3(28, 16), 256, 0, stream>>>(At, WoT, out);
}

// Round 6
// 480.061 us; speedup vs baseline: 1.0011x; 1.0011x over previous
//
#include <hip/hip_runtime.h>
#include <cstdint>
#include <cstddef>

typedef __bf16 bf16x8 __attribute__((ext_vector_type(8)));
typedef __bf16 bf16x4 __attribute__((ext_vector_type(4)));
typedef float f32x4 __attribute__((ext_vector_type(4)));

__device__ __forceinline__ uint16_t f2bf(float f) {
    union { float f; uint32_t u; } v; v.f = f;
    uint32_t r = (v.u + 0x7fffu + ((v.u >> 16) & 1u)) >> 16;
    return (uint16_t)r;
}
__device__ __forceinline__ float bf2f(uint16_t h) {
    union { uint32_t u; float f; } v; v.u = ((uint32_t)h) << 16;
    return v.f;
}

// async 16B/lane global->LDS (wave-uniform LDS base; HW scatters lane i at +16i)
__device__ __forceinline__ void gload_lds16(const void* g, void* l) {
    __builtin_amdgcn_global_load_lds(
        (__attribute__((address_space(1))) void*)g,
        (__attribute__((address_space(3))) void*)l, 16, 0, 0);
}

// ---------------------------------------------------------------------------
// hidden fp32 -> bf16
// ---------------------------------------------------------------------------
__global__ __launch_bounds__(256) void k_tobf16(const float* __restrict__ X,
                                                uint16_t* __restrict__ Y) {
    int i = (blockIdx.x * 256 + threadIdx.x) * 4;
    f32x4 v = *reinterpret_cast<const f32x4*>(X + i);
    uint2 o;
    o.x = (uint32_t)f2bf(v[0]) | ((uint32_t)f2bf(v[1]) << 16);
    o.y = (uint32_t)f2bf(v[2]) | ((uint32_t)f2bf(v[3]) << 16);
    *reinterpret_cast<uint2*>(Y + i) = o;
}

// ---------------------------------------------------------------------------
// Weight transpose + convert: W (R x C, fp32) -> Wt (C x R, bf16)
// ---------------------------------------------------------------------------
__global__ __launch_bounds__(256) void k_transpose_w(const float* __restrict__ W,
                                                     uint16_t* __restrict__ Wt,
                                                     int R, int C) {
    __shared__ uint16_t tile[32][33];
    int c0 = blockIdx.x * 32;
    int r0 = blockIdx.y * 32;
    int t = threadIdx.x;
    int tc = t & 31, tr = t >> 5;
#pragma unroll
    for (int i = 0; i < 4; ++i) {
        int r = tr * 4 + i;
        tile[r][tc] = f2bf(W[(size_t)(r0 + r) * C + c0 + tc]);
    }
    __syncthreads();
#pragma unroll
    for (int i = 0; i < 4; ++i) {
        int c = tr * 4 + i;
        Wt[(size_t)(c0 + c) * R + r0 + tc] = tile[tc][c];
    }
}

// ---------------------------------------------------------------------------
// V transpose: V (2048 x 512 bf16) -> Vt (4 x 128 x 2048 bf16)
// ---------------------------------------------------------------------------
__global__ __launch_bounds__(256) void k_transpose_v(const uint16_t* __restrict__ V,
                                                     uint16_t* __restrict__ Vt) {
    __shared__ uint16_t tile[32][33];
    int c0 = blockIdx.x * 32;
    int s0 = blockIdx.y * 32;
    int t = threadIdx.x;
    int tc = t & 31, tr = t >> 5;
#pragma unroll
    for (int i = 0; i < 4; ++i) {
        int s = tr * 4 + i;
        tile[s][tc] = V[(size_t)(s0 + s) * 512 + c0 + tc];
    }
    __syncthreads();
#pragma unroll
    for (int i = 0; i < 4; ++i) {
        int c = c0 + tr * 4 + i;
        Vt[(size_t)c * 2048 + s0 + tc] = tile[tc][tr * 4 + i];
    }
}

// ---------------------------------------------------------------------------
// RoPE in place. Q scaled by (1/sqrt(128))*log2(e) for exp2-domain softmax.
// ---------------------------------------------------------------------------
__global__ __launch_bounds__(256) void k_rope(uint16_t* __restrict__ Q,
                                              uint16_t* __restrict__ K,
                                              const int* __restrict__ pos_ids) {
    int idx = blockIdx.x * 256 + threadIdx.x;
    int d = idx & 63;
    int s = idx >> 6;
    float pos = (float)pos_ids[s];
    float ang = pos * exp2f((float)d * (-19.931568569324174f / 64.0f));
    float cs = cosf(ang), sn = sinf(ang);
    const float qscale = 0.08838834764831845f * 1.4426950408889634f;
    uint16_t* q = Q + (size_t)s * 3584 + d;
#pragma unroll
    for (int h = 0; h < 28; ++h) {
        float x1 = bf2f(q[h * 128]);
        float x2 = bf2f(q[h * 128 + 64]);
        q[h * 128]      = f2bf((x1 * cs - x2 * sn) * qscale);
        q[h * 128 + 64] = f2bf((x2 * cs + x1 * sn) * qscale);
    }
    uint16_t* k = K + (size_t)s * 512 + d;
#pragma unroll
    for (int h = 0; h < 4; ++h) {
        float x1 = bf2f(k[h * 128]);
        float x2 = bf2f(k[h * 128 + 64]);
        k[h * 128]      = f2bf(x1 * cs - x2 * sn);
        k[h * 128 + 64] = f2bf(x2 * cs + x1 * sn);
    }
}

// ---------------------------------------------------------------------------
// m97-style GEMM: 128x128 tile, BK=32, global_load_lds width-16 staging.
// T1 XCD swizzle kept. 2-barrier structure kept deliberately: explicit dbuf
// regressed in learn_hip m99/m100/m139 (839-890 vs 912 TF at this tile).
// ---------------------------------------------------------------------------
#define BK 32

__global__ __launch_bounds__(256) void k_gemm_qkv(
    const uint16_t* __restrict__ A,
    const uint16_t* __restrict__ WqT,
    const uint16_t* __restrict__ WkT,
    const uint16_t* __restrict__ WvT,
    uint16_t* __restrict__ Q,
    uint16_t* __restrict__ K,
    uint16_t* __restrict__ V)
{
    __shared__ uint16_t Als[128 * BK];
    __shared__ uint16_t Bls[128 * BK];

    int bid = blockIdx.x + blockIdx.y * 36;          // 0..575
    int rid = (bid & 7) * 72 + (bid >> 3);           // XCD-chunked remap
    int nt = rid % 36;
    int m0 = (rid / 36) * 128;

    const uint16_t* Bt; uint16_t* dst; int dstStride; int colBase;
    if (nt < 28)      { Bt = WqT + (size_t)nt * 128 * 3584;        dst = Q; dstStride = 3584; colBase = nt * 128; }
    else if (nt < 32) { Bt = WkT + (size_t)(nt - 28) * 128 * 3584; dst = K; dstStride = 512;  colBase = (nt - 28) * 128; }
    else              { Bt = WvT + (size_t)(nt - 32) * 128 * 3584; dst = V; dstStride = 512;  colBase = (nt - 32) * 128; }

    int tid = threadIdx.x;
    int w = tid >> 6, lane = tid & 63, quad = lane >> 4, l15 = lane & 15;
    int wm = (w >> 1) * 64, wn = (w & 1) * 64;

    int lrow = lane >> 2;
    int lcol = (lane & 3) * 8;

    const uint16_t* aS = A  + (size_t)(m0 + w * 32 + lrow) * 3584 + lcol;
    const uint16_t* bS = Bt + (size_t)(w * 32 + lrow) * 3584 + lcol;
    uint16_t* aD0 = &Als[(w * 32) * BK];
    uint16_t* aD1 = &Als[(w * 32 + 16) * BK];
    uint16_t* bD0 = &Bls[(w * 32) * BK];
    uint16_t* bD1 = &Bls[(w * 32 + 16) * BK];

    f32x4 acc[4][4] = {};

    for (int k0 = 0; k0 < 3584; k0 += BK) {
        __syncthreads();
        gload_lds16(aS + k0, aD0);
        gload_lds16(aS + k0 + (size_t)16 * 3584, aD1);
        gload_lds16(bS + k0, bD0);
        gload_lds16(bS + k0 + (size_t)16 * 3584, bD1);
        __syncthreads();

        bf16x8 af[4], bfr[4];
#pragma unroll
        for (int i = 0; i < 4; ++i)
            af[i] = *reinterpret_cast<const bf16x8*>(&Als[(wm + i * 16 + l15) * BK + quad * 8]);
#pragma unroll
        for (int j = 0; j < 4; ++j)
            bfr[j] = *reinterpret_cast<const bf16x8*>(&Bls[(wn + j * 16 + l15) * BK + quad * 8]);
#pragma unroll
        for (int i = 0; i < 4; ++i)
#pragma unroll
            for (int j = 0; j < 4; ++j)
                acc[i][j] = __builtin_amdgcn_mfma_f32_16x16x32_bf16(af[i], bfr[j], acc[i][j], 0, 0, 0);
    }

#pragma unroll
    for (int i = 0; i < 4; ++i)
#pragma unroll
        for (int r = 0; r < 4; ++r) {
            int grow = m0 + wm + i * 16 + quad * 4 + r;
#pragma unroll
            for (int j = 0; j < 4; ++j) {
                int gcol = colBase + wn + j * 16 + l15;
                dst[(size_t)grow * dstStride + gcol] = f2bf(acc[i][j][r]);
            }
        }
}

__global__ __launch_bounds__(256) void k_gemm_o(
    const uint16_t* __restrict__ A,
    const uint16_t* __restrict__ WoT,
    float* __restrict__ out)
{
    __shared__ uint16_t Als[128 * BK];
    __shared__ uint16_t Bls[128 * BK];

    int bid = blockIdx.x + blockIdx.y * 28;          // 0..447
    int rid = (bid & 7) * 56 + (bid >> 3);           // XCD-chunked remap
    int nt = rid % 28;
    int m0 = (rid / 28) * 128;
    const uint16_t* Bt = WoT + (size_t)nt * 128 * 3584;

    int tid = threadIdx.x;
    int w = tid >> 6, lane = tid & 63, quad = lane >> 4, l15 = lane & 15;
    int wm = (w >> 1) * 64, wn = (w & 1) * 64;

    int lrow = lane >> 2;
    int lcol = (lane & 3) * 8;

    const uint16_t* aS = A  + (size_t)(m0 + w * 32 + lrow) * 3584 + lcol;
    const uint16_t* bS = Bt + (size_t)(w * 32 + lrow) * 3584 + lcol;
    uint16_t* aD0 = &Als[(w * 32) * BK];
    uint16_t* aD1 = &Als[(w * 32 + 16) * BK];
    uint16_t* bD0 = &Bls[(w * 32) * BK];
    uint16_t* bD1 = &Bls[(w * 32 + 16) * BK];

    f32x4 acc[4][4] = {};

    for (int k0 = 0; k0 < 3584; k0 += BK) {
        __syncthreads();
        gload_lds16(aS + k0, aD0);
        gload_lds16(aS + k0 + (size_t)16 * 3584, aD1);
        gload_lds16(bS + k0, bD0);
        gload_lds16(bS + k0 + (size_t)16 * 3584, bD1);
        __syncthreads();

        bf16x8 af[4], bfr[4];
#pragma unroll
        for (int i = 0; i < 4; ++i)
            af[i] = *reinterpret_cast<const bf16x8*>(&Als[(wm + i * 16 + l15) * BK + quad * 8]);
#pragma unroll
        for (int j = 0; j < 4; ++j)
            bfr[j] = *reinterpret_cast<const bf16x8*>(&Bls[(wn + j * 16 + l15) * BK + quad * 8]);
#pragma unroll
        for (int i = 0; i < 4; ++i)
#pragma unroll
            for (int j = 0; j < 4; ++j)
                acc[i][j] = __builtin_amdgcn_mfma_f32_16x16x32_bf16(af[i], bfr[j], acc[i][j], 0, 0, 0);
    }

#pragma unroll
    for (int i = 0; i < 4; ++i)
#pragma unroll
        for (int r = 0; r < 4; ++r) {
            int grow = m0 + wm + i * 16 + quad * 4 + r;
#pragma unroll
            for (int j = 0; j < 4; ++j) {
                int gcol = nt * 128 + wn + j * 16 + l15;
                out[(size_t)grow * 3584 + gcol] = acc[i][j][r];
            }
        }
}

// ---------------------------------------------------------------------------
// Flash attention, split-K within block, swapped QK^T.
// This round: occupancy push. (1) epilogue combines in two 64-col halves
// through a 16KB AccH (LDS 44->27.6KB); (2) V frags split 4+4 (vf at tile
// top, vg post-softmax) to cut peak live registers ~16 (unified VGPR+AGPR
// below the 170 = 3-waves/SIMD threshold); (3) T5 setprio around MFMA
// clusters (m191: +4-7% on barrier-free attn blocks).
// ---------------------------------------------------------------------------
#define FPLD 40

__global__ __launch_bounds__(256, 2) void k_flash(
    const uint16_t* __restrict__ Q,    // 2048x3584 (roped, *1/sqrt(d)*log2e)
    const uint16_t* __restrict__ K,    // 2048x512  (roped)
    const uint16_t* __restrict__ Vt,   // 4x128x2048
    uint16_t* __restrict__ O)          // 2048x3584
{
    __shared__ uint16_t Pls[4][32 * FPLD];   // 10240 B
    __shared__ uint16_t AccH[4][32 * 64];    // 16384 B
    __shared__ float    Ml[4][32][2];        // 1024 B

    int h  = blockIdx.x;               // 0..27
    int qb = 63 - (int)blockIdx.y;     // heavy first
    int kvh = h / 7;
    int tid = threadIdx.x;
    int w = tid >> 6, lane = tid & 63, quad = lane >> 4, l15 = lane & 15;
    int q0 = qb * 32;

    const uint16_t* Kh = K + kvh * 128;
    const uint16_t* Vh = Vt + (size_t)kvh * 128 * 2048;
    __bf16* Pw = reinterpret_cast<__bf16*>(&Pls[w][0]);

    // Q fragments: 32 rows (2 x 16); serves as B-operand of swapped mfma.
    bf16x8 qf[2][4];
#pragma unroll
    for (int s = 0; s < 2; ++s) {
        const uint16_t* qp = Q + (size_t)(q0 + s * 16 + l15) * 3584 + h * 128 + quad * 8;
#pragma unroll
        for (int c = 0; c < 4; ++c)
            qf[s][c] = *reinterpret_cast<const bf16x8*>(qp + c * 32);
    }

    f32x4 acc[2][8] = {};
    float m_i[2], l_i[2];
    m_i[0] = m_i[1] = -1e30f;
    l_i[0] = l_i[1] = 0.f;

    int tmax = qb;                     // tiles 0..qb (32 keys each)
    bf16x8 kf[8];
    int t = w;
    if (t <= tmax) {                   // prefetch first owned K tile
        const uint16_t* kp = Kh + (size_t)(t * 32 + l15) * 512 + quad * 8;
#pragma unroll
        for (int nt = 0; nt < 2; ++nt)
#pragma unroll
            for (int c = 0; c < 4; ++c)
                kf[nt * 4 + c] = *reinterpret_cast<const bf16x8*>(kp + (size_t)nt * 16 * 512 + c * 32);
    }

    for (; t <= tmax; t += 4) {
        int kb = t * 32;
        const uint16_t* vp = Vh + (size_t)l15 * 2048 + kb + quad * 8;
        // first half of V frags (d 0..63); second half issued post-softmax
        bf16x8 vf[4];
#pragma unroll
        for (int dt = 0; dt < 4; ++dt)
            vf[dt] = *reinterpret_cast<const bf16x8*>(vp + (size_t)dt * 16 * 2048);

        // QK^T swapped: sc[s][nt][r] = S[key=kb+nt*16+quad*4+r][q=q0+s*16+l15]
        f32x4 sc[2][2] = {};
        __builtin_amdgcn_s_setprio(1);
#pragma unroll
        for (int nt = 0; nt < 2; ++nt)
#pragma unroll
            for (int c = 0; c < 4; ++c) {
                sc[0][nt] = __builtin_amdgcn_mfma_f32_16x16x32_bf16(kf[nt * 4 + c], qf[0][c], sc[0][nt], 0, 0, 0);
                sc[1][nt] = __builtin_amdgcn_mfma_f32_16x16x32_bf16(kf[nt * 4 + c], qf[1][c], sc[1][nt], 0, 0, 0);
            }
        __builtin_amdgcn_s_setprio(0);

        // prefetch next owned K tile (hidden under softmax + PV)
        int tn = t + 4;
        if (tn <= tmax) {
            const uint16_t* kp = Kh + (size_t)(tn * 32 + l15) * 512 + quad * 8;
#pragma unroll
            for (int nt = 0; nt < 2; ++nt)
#pragma unroll
                for (int c = 0; c < 4; ++c)
                    kf[nt * 4 + c] = *reinterpret_cast<const bf16x8*>(kp + (size_t)nt * 16 * 512 + c * 32);
        }

        // causal mask (only possible on the last tile: kb+31 > q0)
        if (kb + 31 > q0) {
#pragma unroll
            for (int s = 0; s < 2; ++s) {
                int row = q0 + s * 16 + l15;
#pragma unroll
                for (int nt = 0; nt < 2; ++nt) {
                    int keyb = kb + nt * 16 + quad * 4;
#pragma unroll
                    for (int r = 0; r < 4; ++r)
                        if (keyb + r > row) sc[s][nt][r] = -1e30f;
                }
            }
        }

        // online softmax: lane owns one q-row per s
#pragma unroll
        for (int s = 0; s < 2; ++s) {
            float mx = fmaxf(fmaxf(fmaxf(sc[s][0][0], sc[s][0][1]), fmaxf(sc[s][0][2], sc[s][0][3])),
                             fmaxf(fmaxf(sc[s][1][0], sc[s][1][1]), fmaxf(sc[s][1][2], sc[s][1][3])));
            mx = fmaxf(mx, __shfl_xor(mx, 16));
            mx = fmaxf(mx, __shfl_xor(mx, 32));
            bool nd = mx > m_i[s] + 11.5f;       // T13 defer-rescale
            float mn = nd ? mx : m_i[s];
            float alf = __builtin_amdgcn_exp2f(m_i[s] - mn);
            m_i[s] = mn;

            float rs = 0.f;
#pragma unroll
            for (int nt = 0; nt < 2; ++nt)
#pragma unroll
                for (int r = 0; r < 4; ++r) {
                    float p = __builtin_amdgcn_exp2f(sc[s][nt][r] - mn);
                    sc[s][nt][r] = p;
                    rs += p;
                }
            rs += __shfl_xor(rs, 16);
            rs += __shfl_xor(rs, 32);
            l_i[s] = l_i[s] * alf + rs;

            if (__any(nd)) {           // rare: rescale acc rows (q=quad*4+r)
                f32x4 alfr;
#pragma unroll
                for (int r = 0; r < 4; ++r)
                    alfr[r] = __shfl(alf, quad * 4 + r);
#pragma unroll
                for (int dt = 0; dt < 8; ++dt)
                    acc[s][dt] *= alfr;
            }

            // packed P-store: row q=s*16+l15, keys nt*16+quad*4..+3 (8B each)
#pragma unroll
            for (int nt = 0; nt < 2; ++nt) {
                bf16x4 pk;
#pragma unroll
                for (int r = 0; r < 4; ++r) pk[r] = (__bf16)sc[s][nt][r];
                *reinterpret_cast<bf16x4*>(&Pw[(s * 16 + l15) * FPLD + nt * 16 + quad * 4]) = pk;
            }
        }

        // second half of V frags (d 64..127): in flight under PV first half
        bf16x8 vg[4];
#pragma unroll
        for (int dt = 0; dt < 4; ++dt)
            vg[dt] = *reinterpret_cast<const bf16x8*>(vp + (size_t)(dt + 4) * 16 * 2048);

        // PV: 32 q x 128 d over 32 keys (wave-private LDS, in-wave ordering)
        bf16x8 pf0 = *reinterpret_cast<const bf16x8*>(&Pw[l15 * FPLD + quad * 8]);
        bf16x8 pf1 = *reinterpret_cast<const bf16x8*>(&Pw[(16 + l15) * FPLD + quad * 8]);
        __builtin_amdgcn_s_setprio(1);
#pragma unroll
        for (int dt = 0; dt < 4; ++dt) {
            acc[0][dt] = __builtin_amdgcn_mfma_f32_16x16x32_bf16(pf0, vf[dt], acc[0][dt], 0, 0, 0);
            acc[1][dt] = __builtin_amdgcn_mfma_f32_16x16x32_bf16(pf1, vf[dt], acc[1][dt], 0, 0, 0);
        }
#pragma unroll
        for (int dt = 0; dt < 4; ++dt) {
            acc[0][dt + 4] = __builtin_amdgcn_mfma_f32_16x16x32_bf16(pf0, vg[dt], acc[0][dt + 4], 0, 0, 0);
            acc[1][dt + 4] = __builtin_amdgcn_mfma_f32_16x16x32_bf16(pf1, vg[dt], acc[1][dt + 4], 0, 0, 0);
        }
        __builtin_amdgcn_s_setprio(0);
    }

    // ---- combine across the 4 waves, two 64-col halves through AccH ----
    if (lane < 16) {                   // quad 0 lanes hold full stats for q=l15
        Ml[w][lane][0]      = m_i[0];
        Ml[w][lane][1]      = l_i[0];
        Ml[w][16 + lane][0] = m_i[1];
        Ml[w][16 + lane][1] = l_i[1];
    }

#pragma unroll
    for (int half = 0; half < 2; ++half) {
        __bf16* As = reinterpret_cast<__bf16*>(&AccH[w][0]);
#pragma unroll
        for (int s = 0; s < 2; ++s)
#pragma unroll
            for (int dt = 0; dt < 4; ++dt)
#pragma unroll
                for (int r = 0; r < 4; ++r)
                    As[(s * 16 + quad * 4 + r) * 64 + dt * 16 + l15] = (__bf16)acc[s][half * 4 + dt][r];
        __syncthreads();   // half 0: also orders Ml writes before reads

        {
            int rowl = w * 8 + (lane >> 3);
            int c8 = (lane & 7) * 8;
            float m0 = Ml[0][rowl][0], m1 = Ml[1][rowl][0], m2 = Ml[2][rowl][0], m3 = Ml[3][rowl][0];
            float M = fmaxf(fmaxf(m0, m1), fmaxf(m2, m3));
            float s0 = __builtin_amdgcn_exp2f(m0 - M);
            float s1 = __builtin_amdgcn_exp2f(m1 - M);
            float s2 = __builtin_amdgcn_exp2f(m2 - M);
            float s3 = __builtin_amdgcn_exp2f(m3 - M);
            float lt = Ml[0][rowl][1] * s0 + Ml[1][rowl][1] * s1 +
                       Ml[2][rowl][1] * s2 + Ml[3][rowl][1] * s3;
            float inv = __builtin_amdgcn_rcpf(lt);
            float sw[4] = {s0, s1, s2, s3};

            float o[8];
#pragma unroll
            for (int j = 0; j < 8; ++j) o[j] = 0.f;
#pragma unroll
            for (int sl = 0; sl < 4; ++sl) {
                const uint16_t* src = &AccH[sl][rowl * 64 + c8];
                float ssc = sw[sl];
#pragma unroll
                for (int j = 0; j < 8; ++j)
                    o[j] += bf2f(src[j]) * ssc;
            }
            uint16_t ob[8];
#pragma unroll
            for (int j = 0; j < 8; ++j) ob[j] = f2bf(o[j] * inv);
            uint16_t* op = O + (size_t)(q0 + rowl) * 3584 + h * 128 + half * 64 + c8;
            *reinterpret_cast<uint4*>(op) = *reinterpret_cast<uint4*>(&ob[0]);
        }
        if (half == 0) __syncthreads();   // combine reads done before half-1 writes
    }
}

// ---------------------------------------------------------------------------
extern "C" void kernel_launch(void* const* d_in, const int* in_sizes, int n_in,
                              void* d_out, int out_size, void* d_ws, size_t ws_size,
                              hipStream_t stream) {
    const float* hidden = (const float*)d_in[0];
    const int*   pos    = (const int*)d_in[1];
    const float* Wq     = (const float*)d_in[2];
    const float* Wk     = (const float*)d_in[3];
    const float* Wv     = (const float*)d_in[4];
    const float* Wo     = (const float*)d_in[5];
    float* out = (float*)d_out;

    char* ws = (char*)d_ws;
    size_t o = 0;
    uint16_t* WqT = (uint16_t*)(ws + o); o += (size_t)3584 * 3584 * 2;
    uint16_t* WkT = (uint16_t*)(ws + o); o += (size_t)512  * 3584 * 2;
    uint16_t* WvT = (uint16_t*)(ws + o); o += (size_t)512  * 3584 * 2;
    uint16_t* WoT = (uint16_t*)(ws + o); o += (size_t)3584 * 3584 * 2;
    uint16_t* Xb  = (uint16_t*)(ws + o); o += (size_t)2048 * 3584 * 2;  // aliased as At
    uint16_t* Qb  = (uint16_t*)(ws + o); o += (size_t)2048 * 3584 * 2;
    uint16_t* Kb  = (uint16_t*)(ws + o); o += (size_t)2048 * 512  * 2;
    uint16_t* Vb  = (uint16_t*)(ws + o); o += (size_t)2048 * 512  * 2;
    uint16_t* Vt  = (uint16_t*)(ws + o); o += (size_t)2048 * 512  * 2;
    uint16_t* At  = Xb;

    k_tobf16<<<dim3(7168), 256, 0, stream>>>(hidden, Xb);
    k_transpose_w<<<dim3(112, 112), 256, 0, stream>>>(Wq, WqT, 3584, 3584);
    k_transpose_w<<<dim3(16, 112),  256, 0, stream>>>(Wk, WkT, 3584, 512);
    k_transpose_w<<<dim3(16, 112),  256, 0, stream>>>(Wv, WvT, 3584, 512);
    k_transpose_w<<<dim3(112, 112), 256, 0, stream>>>(Wo, WoT, 3584, 3584);

    k_gemm_qkv<<<dim3(36, 16), 256, 0, stream>>>(Xb, WqT, WkT, WvT, Qb, Kb, Vb);
    k_rope<<<dim3(512), 256, 0, stream>>>(Qb, Kb, pos);
    k_transpose_v<<<dim3(16, 64), 256, 0, stream>>>(Vb, Vt);
    k_flash<<<dim3(28, 64), 256, 0, stream>>>(Qb, Kb, Vt, At);
    k_gemm_o<<<dim3(28, 16), 256, 0, stream>>>(At, WoT, out);
}